// Round 7
// baseline (404.389 us; speedup 1.0000x reference)
//
#include <hip/hip_runtime.h>
#include <hip/hip_bf16.h>
#include <math.h>

// PillarHist: per-row 64-bin hist (count/mean_z/mean_r interleaved) -> Linear(192->64) -> BN(train) -> ReLU
// FUSED single-pass design (R7):
// k0 (16 blocks): permuted bf16 B-fragments into d_ws + zero BN totals + zero grid-barrier ctr.
// k1_fused (1563 blocks, 128 thr = one wave pair, 4 tiles x 16 rows = 64 rows/block):
//     Per tile (proven R2 body): load z/r (uint2) -> LDS u64-packed hist (ONE ds_add_u64/point)
//     -> pair barrier -> 24 MFMAs from bin-grouped ds_read_b128 decode, B-frags double-buffered
//     from L2. Accumulators acc[4][2] (+bias) stay in REGISTERS.
//     Then: BN fixed-point partials -> device atomics -> hand-rolled GRID BARRIER
//     (counter spin; co-residency: 1563 blocks <= 2048 = 8 blocks/CU x 256 @ launch_bounds(128,4),
//     LDS 8.4KB -> 19/CU, slots 16/CU) -> each wave computes mu/var/a/c from replica totals
//     (bit-identical math to the old k3) -> applies BN+ReLU to registers -> ONE output write.
//     Eliminates the 25.6 MB pre-BN x store + 25.6 MB k3 re-read + the k3 dispatch.

typedef __attribute__((ext_vector_type(8))) short bf16x8;   // 8 bf16 = 4 VGPRs = 16 B
typedef __attribute__((ext_vector_type(4))) float f32x4;
typedef __attribute__((ext_vector_type(4))) int   i32x4;

#define ZMINF   (-3.0f)
#define INV_BIN 16.0f            // 1/BIN_SIZE (exact pow2)
#define QS      8192.0f          // 2^13 payload scale
#define INV_QS  (1.0f / 8192.0f)
#define PBIASF  65536.0f         // 2^16 payload bias (covers |z|<8; 64*max_payload < 2^24)
#define PBIASI  65536
#define CBIT    16777216         // 2^24 count increment (hi word only)
#define TSC     16777216.0f     // 2^24 fixed-point scale for BN totals
#define INV_TSC (1.0f / 16777216.0f)
#define REPS    16               // BN total replicas
#define RSTRIDE 66               // u64 per row (64 bins + 2 pad -> bank spread)
#define TILES   4                // 16-row tiles per block -> grid 1563

__device__ __forceinline__ short f2bf(float f) {
    __hip_bfloat16 h = __float2bfloat16(f);   // RNE
    return __builtin_bit_cast(short, h);
}

// ---- k0: grid-stride. Permuted W -> bf16 fragments (frag-major [s*4+t][lane][j]) + zero totals+ctr ----
__global__ __launch_bounds__(256)
void k0_prep(const float* __restrict__ W,                  // [64,192]
             short*       __restrict__ wsW,                // [24*64*8] bf16
             unsigned long long* __restrict__ totals)      // [REPS*128 + 1] (last = grid ctr)
{
    const int tid    = blockIdx.x * 256 + threadIdx.x;
    const int stride = gridDim.x * 256;
    for (int e = tid; e < 24 * 64 * 8; e += stride) {
        const int j  = e & 7;
        const int ln = (e >> 3) & 63;
        const int st = e >> 9;                       // s*4+t
        const int s  = st >> 2, t = st & 3;
        const int k  = s * 32 + (ln >> 4) * 8 + j;   // planar k
        const int n  = t * 16 + (ln & 15);           // output channel
        const int wc = (k < 64) ? 3 * k
                     : (k < 128) ? 3 * (k - 64) + 1
                                 : 3 * (k - 128) + 2;
        wsW[e] = f2bf(W[n * 192 + wc]);
    }
    for (int e = tid; e < REPS * 128 + 1; e += stride) totals[e] = 0ull;
}

__global__ __launch_bounds__(128, 4)
void k1_fused(const uint2*  __restrict__ feat2,  // feat as uint2; zw of (row,pt) at (row*64+pt)*2+1
              const int*    __restrict__ nump,   // [M]
              const bf16x8* __restrict__ wsWf,   // [24*64] B fragments (global, L2-hot)
              const float*  __restrict__ bvec,   // [64]
              const float*  __restrict__ gamma,  // [64]
              const float*  __restrict__ beta,   // [64]
              float*        __restrict__ out,    // [M,64] final output (d_out)
              unsigned long long* __restrict__ totals, // [REPS*128] fixed-point sum | sumsq
              unsigned int* __restrict__ ctr,    // grid-barrier counter (zeroed by k0)
              float invM, int M)
{
    __shared__ unsigned long long sH[16 * RSTRIDE];   // 8448 B, reused across tiles

    const int tid  = threadIdx.x;
    const int half = tid >> 6;          // wave 0/1; output half: ch in [half*32, half*32+32)
    const int lane = tid & 63;
    const int col  = lane & 15;
    const int quad = lane >> 4;

    const int gbase0 = blockIdx.x * (16 * TILES);

    const float bias0 = bvec[(half * 2 + 0) * 16 + col];
    const float bias1 = bvec[(half * 2 + 1) * 16 + col];

    float psum[2] = {0.f, 0.f};
    float psq[2]  = {0.f, 0.f};
    f32x4 acc[TILES][2];                 // lives across the grid barrier (32 VGPR)

    #pragma unroll
    for (int t = 0; t < TILES; ++t) {
        const int gbase = gbase0 + t * 16;
        if (gbase < M) {                 // block-uniform guard: barriers inside are safe
            // ---- 8 rows of z/r per wave, one load batch ----
            uint2 zw[8];
            const int npv = nump[min(gbase + half * 8 + (lane & 7), M - 1)];
            #pragma unroll
            for (int uu = 0; uu < 8; ++uu) {
                const int rc = min(gbase + half * 8 + uu, M - 1);
                zw[uu] = feat2[((size_t)rc * 64 + lane) * 2 + 1];
            }

            // ---- zero OWN 8-row strip (overlaps load latency) ----
            {
                i32x4* p4 = (i32x4*)&sH[(size_t)half * 8 * RSTRIDE];
                #pragma unroll
                for (int i = 0; i < 5; ++i) {
                    const int idx = lane + i * 64;
                    if (idx < (8 * RSTRIDE * 2) / 4) p4[idx] = i32x4{0, 0, 0, 0};
                }
            }
            __builtin_amdgcn_wave_barrier();

            // ---- packed hist, own 8 rows: ONE native ds_add_u64 per point ----
            #pragma unroll
            for (int uu = 0; uu < 8; ++uu) {
                const int u = half * 8 + uu;
                int np_u = __builtin_amdgcn_readlane(npv, uu);
                np_u = (gbase + u < M) ? np_u : 0;
                if (lane < np_u) {
                    const float z  = __int_as_float((int)zw[uu].x);
                    const float rr = __int_as_float((int)zw[uu].y);
                    int bi = (int)((z - ZMINF) * INV_BIN);   // trunc, matches astype(int32)
                    bi = min(max(bi, 0), 63);
                    const unsigned long long add =
                        ((unsigned long long)(unsigned)(CBIT + PBIASI + (int)(z * QS)) << 32)
                        | (unsigned)(PBIASI + (int)(rr * QS));
                    atomicAdd(&sH[u * RSTRIDE + bi], add);
                }
            }

            // ---- prefetch plane-0 B-frags ----
            bf16x8 bcur[2], bnxt[2];
            bcur[0] = wsWf[(half * 2 + 0) * 64 + lane];
            bcur[1] = wsWf[(half * 2 + 1) * 64 + lane];

            __syncthreads();   // partner's 8 rows complete & visible

            // ---- MFMA: A rows = col; bin-group g covers bins g*32+quad*8..+7 ----
            f32x4 a0v = {}, a1v = {};
            const int* ar = (const int*)sH + col * (RSTRIDE * 2);
            #pragma unroll
            for (int g = 0; g < 2; ++g) {
                const int o0 = g * 32 + quad * 8;
                const i32x4* ap = (const i32x4*)(ar + 2 * o0);
                const i32x4 b0 = ap[0], b1 = ap[1], b2 = ap[2], b3 = ap[3];
                const int zz[8]  = {b0.y, b0.w, b1.y, b1.w, b2.y, b2.w, b3.y, b3.w};
                const int rrw[8] = {b0.x, b0.z, b1.x, b1.z, b2.x, b2.z, b3.x, b3.z};
                float cnt[8], rcp[8], av[8];
                bf16x8 af;

                // substage A: counts (plane g); prefetch plane 2+g
                bnxt[0] = wsWf[((2 + g) * 4 + half * 2 + 0) * 64 + lane];
                bnxt[1] = wsWf[((2 + g) * 4 + half * 2 + 1) * 64 + lane];
                #pragma unroll
                for (int j = 0; j < 8; ++j) { cnt[j] = (float)(zz[j] >> 24); av[j] = cnt[j]; }
                #pragma unroll
                for (int j = 0; j < 8; ++j) af[j] = f2bf(av[j]);
                a0v = __builtin_amdgcn_mfma_f32_16x16x32_bf16(af, bcur[0], a0v, 0, 0, 0);
                a1v = __builtin_amdgcn_mfma_f32_16x16x32_bf16(af, bcur[1], a1v, 0, 0, 0);
                bcur[0] = bnxt[0]; bcur[1] = bnxt[1];

                // substage B: mean_z (plane 2+g); prefetch plane 4+g
                bnxt[0] = wsWf[((4 + g) * 4 + half * 2 + 0) * 64 + lane];
                bnxt[1] = wsWf[((4 + g) * 4 + half * 2 + 1) * 64 + lane];
                #pragma unroll
                for (int j = 0; j < 8; ++j) {
                    rcp[j] = __builtin_amdgcn_rcpf(cnt[j] + 1e-5f) * INV_QS;
                    const float pay = (float)(zz[j] & 0xFFFFFF);     // exact (<2^24)
                    av[j] = (pay - cnt[j] * PBIASF) * rcp[j];
                }
                #pragma unroll
                for (int j = 0; j < 8; ++j) af[j] = f2bf(av[j]);
                a0v = __builtin_amdgcn_mfma_f32_16x16x32_bf16(af, bcur[0], a0v, 0, 0, 0);
                a1v = __builtin_amdgcn_mfma_f32_16x16x32_bf16(af, bcur[1], a1v, 0, 0, 0);
                bcur[0] = bnxt[0]; bcur[1] = bnxt[1];

                // substage C: mean_r (plane 4+g); prefetch plane 1 when g==0
                if (g == 0) {
                    bnxt[0] = wsWf[(1 * 4 + half * 2 + 0) * 64 + lane];
                    bnxt[1] = wsWf[(1 * 4 + half * 2 + 1) * 64 + lane];
                }
                #pragma unroll
                for (int j = 0; j < 8; ++j)
                    av[j] = ((float)rrw[j] - cnt[j] * PBIASF) * rcp[j];
                #pragma unroll
                for (int j = 0; j < 8; ++j) af[j] = f2bf(av[j]);
                a0v = __builtin_amdgcn_mfma_f32_16x16x32_bf16(af, bcur[0], a0v, 0, 0, 0);
                a1v = __builtin_amdgcn_mfma_f32_16x16x32_bf16(af, bcur[1], a1v, 0, 0, 0);
                bcur[0] = bnxt[0]; bcur[1] = bnxt[1];
            }

            // ---- fold bias in, accumulate BN partials (guarded), keep in registers ----
            #pragma unroll
            for (int i = 0; i < 4; ++i) {
                const int row = gbase + quad * 4 + i;
                const float xv0 = a0v[i] + bias0;
                const float xv1 = a1v[i] + bias1;
                acc[t][0][i] = xv0;
                acc[t][1][i] = xv1;
                if (row < M) {
                    psum[0] += xv0; psq[0] += xv0 * xv0;
                    psum[1] += xv1; psq[1] += xv1 * xv1;
                }
            }

            if (t + 1 < TILES)
                __syncthreads();   // partner done reading strip before next zero
        }
    }

    // ---- BN partials: quad-reduce; lanes 0..31 carry this wave's 32 channels ----
    #pragma unroll
    for (int tt = 0; tt < 2; ++tt) {
        psum[tt] += __shfl_xor(psum[tt], 16);
        psum[tt] += __shfl_xor(psum[tt], 32);
        psq[tt]  += __shfl_xor(psq[tt], 16);
        psq[tt]  += __shfl_xor(psq[tt], 32);
    }
    const float myS = (quad & 1) ? psum[1] : psum[0];
    const float myQ = (quad & 1) ? psq[1]  : psq[0];
    if (lane < 32) {
        unsigned long long* dst = totals + (blockIdx.x & (REPS - 1)) * 128 + half * 32 + lane;
        atomicAdd(dst,      (unsigned long long)(long long)(myS * TSC));
        atomicAdd(dst + 64, (unsigned long long)(long long)(myQ * TSC));
    }

    // ---- GRID BARRIER: all blocks resident by construction (1563 <= 2048) ----
    __syncthreads();   // drains both waves' atomics (vmcnt 0) before arrival
    if (tid == 0) {
        __hip_atomic_fetch_add(ctr, 1u, __ATOMIC_ACQ_REL, __HIP_MEMORY_SCOPE_AGENT);
        while (__hip_atomic_load(ctr, __ATOMIC_ACQUIRE, __HIP_MEMORY_SCOPE_AGENT)
               < (unsigned)gridDim.x)
            __builtin_amdgcn_s_sleep(8);
    }
    __syncthreads();

    // ---- finalize BN per channel (bit-identical to old k3 math) and write output ONCE ----
    float aco[2], cco[2];
    #pragma unroll
    for (int tt = 0; tt < 2; ++tt) {
        const int ch = (half * 2 + tt) * 16 + col;
        long long S = 0, Q = 0;
        #pragma unroll
        for (int rep = 0; rep < REPS; ++rep) {
            S += (long long)totals[rep * 128 + ch];
            Q += (long long)totals[rep * 128 + 64 + ch];
        }
        const float mu   = (float)S * (invM * INV_TSC);
        const float q    = (float)Q * (invM * INV_TSC);
        const float var  = q - mu * mu;
        const float rstd = 1.0f / sqrtf(var + 1e-5f);
        const float a    = gamma[ch] * rstd;
        aco[tt] = a;
        cco[tt] = beta[ch] - mu * a;
    }
    #pragma unroll
    for (int t = 0; t < TILES; ++t) {
        const int gbase = gbase0 + t * 16;
        if (gbase < M) {
            #pragma unroll
            for (int i = 0; i < 4; ++i) {
                const int row = gbase + quad * 4 + i;
                if (row < M) {
                    float* xr = out + (size_t)row * 64 + half * 32 + col;
                    xr[0]  = fmaxf(fmaf(acc[t][0][i], aco[0], cco[0]), 0.f);
                    xr[16] = fmaxf(fmaf(acc[t][1][i], aco[1], cco[1]), 0.f);
                }
            }
        }
    }
}

extern "C" void kernel_launch(void* const* d_in, const int* in_sizes, int n_in,
                              void* d_out, int out_size, void* d_ws, size_t ws_size,
                              hipStream_t stream) {
    const uint2*  feat2 = (const uint2*)d_in[0];   // [M,64,4] fp32 viewed as uint2 pairs
    const int*    nump  = (const int*)d_in[1];     // [M]
    // d_in[2] = coors (unused)
    const float*  W     = (const float*)d_in[3];   // [64,192]
    const float*  bvec  = (const float*)d_in[4];   // [64]
    const float*  gamma = (const float*)d_in[5];   // [64]
    const float*  beta  = (const float*)d_in[6];   // [64]

    const int M = in_sizes[1];
    short* wsW  = (short*)d_ws;                                   // [24*64*8] bf16 B-fragments
    unsigned long long* totals =
        (unsigned long long*)((char*)d_ws + 24 * 64 * 8 * sizeof(short));  // [REPS*128+1] u64
    unsigned int* ctr = (unsigned int*)(totals + REPS * 128);              // grid-barrier ctr

    k0_prep<<<16, 256, 0, stream>>>(W, wsW, totals);

    const int nblk = (M + 16 * TILES - 1) / (16 * TILES);   // 64 rows/block -> 1563 blocks
    k1_fused<<<nblk, 128, 0, stream>>>(feat2, nump, (const bf16x8*)wsW, bvec, gamma, beta,
                                       (float*)d_out, totals, ctr, 1.0f / (float)M, M);
}

// Round 8
// 186.870 us; speedup vs baseline: 2.1640x; 2.1640x over previous
//
#include <hip/hip_runtime.h>
#include <hip/hip_bf16.h>
#include <math.h>

// PillarHist: per-row 64-bin hist (count/mean_z/mean_r interleaved) -> Linear(192->64) -> BN(train) -> ReLU
// R8 = REVERT to the best-measured configuration (R2, 185.0 us) + ONE bounded fix:
//   k3's grid was 391 blocks (~1.5/CU, ~6 waves/CU) for a 51.2 MB memory-bound pass ->
//   raised to up-to-2048 grid-stride blocks (G11). k0/k1 are bit-identical to R2.
// History (all harness-measured): R0 pair-share 193.2 | R2 u64-hist+bin-group 185.0 |
//   R3 4-tile pipeline 190.1 (residency loss) | R4 2-tile 193.8 | R5 uint4 loads 186.1 |
//   R6 fission 213.8 | R7 grid-sync fusion 404.4 (agent-scope spin barrier ~230 us penalty).
// k1 structural wall: ~45-50 us with all pipes <15% busy across 30-48% occupancy, packed vs
//   split atomics, 1-4 tile pipelining, 8B-strided vs 16B-contiguous loads -> latency-bound
//   local minimum; documented here so future edits don't re-walk the same dead ends.

typedef __attribute__((ext_vector_type(8))) short bf16x8;   // 8 bf16 = 4 VGPRs = 16 B
typedef __attribute__((ext_vector_type(4))) float f32x4;
typedef __attribute__((ext_vector_type(4))) int   i32x4;

#define ZMINF   (-3.0f)
#define INV_BIN 16.0f            // 1/BIN_SIZE (exact pow2)
#define QS      8192.0f          // 2^13 payload scale
#define INV_QS  (1.0f / 8192.0f)
#define PBIASF  65536.0f         // 2^16 payload bias (covers |z|<8; 64*max_payload < 2^24)
#define PBIASI  65536
#define CBIT    16777216         // 2^24 count increment (hi word only)
#define TSC     16777216.0f     // 2^24 fixed-point scale for BN totals
#define INV_TSC (1.0f / 16777216.0f)
#define REPS    16               // BN total replicas
#define RSTRIDE 66               // u64 per row (64 bins + 2 pad -> bank spread)

__device__ __forceinline__ short f2bf(float f) {
    __hip_bfloat16 h = __float2bfloat16(f);   // RNE
    return __builtin_bit_cast(short, h);
}

// ---- k0: grid-stride. Permuted W -> bf16 fragments (frag-major [s*4+t][lane][j]) + zero totals ----
__global__ __launch_bounds__(256)
void k0_prep(const float* __restrict__ W,                  // [64,192]
             short*       __restrict__ wsW,                // [24*64*8] bf16
             unsigned long long* __restrict__ totals)      // [REPS*128]
{
    const int tid    = blockIdx.x * 256 + threadIdx.x;
    const int stride = gridDim.x * 256;
    for (int e = tid; e < 24 * 64 * 8; e += stride) {
        const int j  = e & 7;
        const int ln = (e >> 3) & 63;
        const int st = e >> 9;                       // s*4+t
        const int s  = st >> 2, t = st & 3;
        const int k  = s * 32 + (ln >> 4) * 8 + j;   // planar k
        const int n  = t * 16 + (ln & 15);           // output channel
        const int wc = (k < 64) ? 3 * k
                     : (k < 128) ? 3 * (k - 64) + 1
                                 : 3 * (k - 128) + 2;
        wsW[e] = f2bf(W[n * 192 + wc]);
    }
    for (int e = tid; e < REPS * 128; e += stride) totals[e] = 0ull;
}

__global__ __launch_bounds__(128, 8)
void k1_hist_mfma(const uint2*  __restrict__ feat2,  // feat as uint2; zw of (row,pt) at (row*64+pt)*2+1
                  const int*    __restrict__ nump,   // [M]
                  const bf16x8* __restrict__ wsWf,   // [24*64] B fragments (global, L2-hot)
                  const float*  __restrict__ bvec,   // [64]
                  float*        __restrict__ xout,   // [M,64] pre-BN x (d_out)
                  unsigned long long* __restrict__ totals, // [REPS*128] fixed-point sum | sumsq
                  int M)
{
    __shared__ unsigned long long sH[16 * RSTRIDE];   // 8448 B: 16 rows x (64 bins u64 + pad)

    const int tid  = threadIdx.x;
    const int wave = tid >> 6;          // 0,1 — one pair per block
    const int lane = tid & 63;
    const int col  = lane & 15;
    const int quad = lane >> 4;
    const int half = wave;              // output half: t in {2*half, 2*half+1}

    const int gbase = blockIdx.x * 16;
    float psum[2] = {0.f, 0.f};
    float psq[2]  = {0.f, 0.f};
    bf16x8 bcur[2];

    if (gbase < M) {
        // ---- 8 rows of z/w per wave in ONE load batch (uint2 = 8 B/lane; 16 VGPRs) ----
        uint2 zw[8];
        const int npv = nump[min(gbase + half * 8 + (lane & 7), M - 1)];  // lanes 0..7 hold own rows
        #pragma unroll
        for (int uu = 0; uu < 8; ++uu) {
            const int rc = min(gbase + half * 8 + uu, M - 1);
            zw[uu] = feat2[((size_t)rc * 64 + lane) * 2 + 1];
        }

        // ---- zero OWN 8-row strip (8*66 u64 = 4224 B); overlaps load latency ----
        {
            i32x4* p4 = (i32x4*)&sH[(size_t)half * 8 * RSTRIDE];
            #pragma unroll
            for (int i = 0; i < 5; ++i) {
                const int idx = lane + i * 64;
                if (idx < (8 * RSTRIDE * 2) / 4) p4[idx] = i32x4{0, 0, 0, 0};
            }
        }
        __builtin_amdgcn_wave_barrier();

        // ---- packed hist, own 8 rows: ONE native ds_add_u64 per point ----
        #pragma unroll
        for (int uu = 0; uu < 8; ++uu) {
            const int u = half * 8 + uu;                         // row within block strip
            int np_u = __builtin_amdgcn_readlane(npv, uu);
            np_u = (gbase + u < M) ? np_u : 0;                   // uniform tail guard
            if (lane < np_u) {
                const float z  = __int_as_float((int)zw[uu].x);
                const float rr = __int_as_float((int)zw[uu].y);
                int bi = (int)((z - ZMINF) * INV_BIN);           // trunc, matches astype(int32)
                bi = min(max(bi, 0), 63);
                const unsigned long long add =
                    ((unsigned long long)(unsigned)(CBIT + PBIASI + (int)(z * QS)) << 32)
                    | (unsigned)(PBIASI + (int)(rr * QS));
                atomicAdd(&sH[u * RSTRIDE + bi], add);
            }
        }

        // ---- prefetch plane-0 B-frags (L2-hot) so they land by the barrier drain ----
        bcur[0] = wsWf[(half * 2 + 0) * 64 + lane];
        bcur[1] = wsWf[(half * 2 + 1) * 64 + lane];
    }

    __syncthreads();   // pair-exact: partner's 8 rows complete & visible

    if (gbase < M) {
        // ---- MFMA: A rows = col; bin-group g covers bins g*32+quad*8..+7 (z+r in one read run) ----
        f32x4 acc[2] = {};
        bf16x8 bnxt[2];
        const int* ar = (const int*)sH + col * (RSTRIDE * 2);   // row col, int view
        #pragma unroll
        for (int g = 0; g < 2; ++g) {
            const int o0 = g * 32 + quad * 8;                   // first bin of this lane's slice
            const i32x4* ap = (const i32x4*)(ar + 2 * o0);      // 64 B contiguous: 8 bins (r,z)x4
            const i32x4 a0 = ap[0], a1 = ap[1], a2 = ap[2], a3 = ap[3];
            const int zz[8]  = {a0.y, a0.w, a1.y, a1.w, a2.y, a2.w, a3.y, a3.w};
            const int rrw[8] = {a0.x, a0.z, a1.x, a1.z, a2.x, a2.z, a3.x, a3.z};
            float cnt[8], rcp[8], av[8];
            bf16x8 af;

            // -- substage A: counts (plane g); prefetch plane 2+g --
            bnxt[0] = wsWf[((2 + g) * 4 + half * 2 + 0) * 64 + lane];
            bnxt[1] = wsWf[((2 + g) * 4 + half * 2 + 1) * 64 + lane];
            #pragma unroll
            for (int j = 0; j < 8; ++j) { cnt[j] = (float)(zz[j] >> 24); av[j] = cnt[j]; }
            #pragma unroll
            for (int j = 0; j < 8; ++j) af[j] = f2bf(av[j]);
            acc[0] = __builtin_amdgcn_mfma_f32_16x16x32_bf16(af, bcur[0], acc[0], 0, 0, 0);
            acc[1] = __builtin_amdgcn_mfma_f32_16x16x32_bf16(af, bcur[1], acc[1], 0, 0, 0);
            bcur[0] = bnxt[0]; bcur[1] = bnxt[1];

            // -- substage B: mean_z (plane 2+g); prefetch plane 4+g --
            bnxt[0] = wsWf[((4 + g) * 4 + half * 2 + 0) * 64 + lane];
            bnxt[1] = wsWf[((4 + g) * 4 + half * 2 + 1) * 64 + lane];
            #pragma unroll
            for (int j = 0; j < 8; ++j) {
                rcp[j] = __builtin_amdgcn_rcpf(cnt[j] + 1e-5f) * INV_QS;
                const float pay = (float)(zz[j] & 0xFFFFFF);            // exact (<2^24)
                av[j] = (pay - cnt[j] * PBIASF) * rcp[j];
            }
            #pragma unroll
            for (int j = 0; j < 8; ++j) af[j] = f2bf(av[j]);
            acc[0] = __builtin_amdgcn_mfma_f32_16x16x32_bf16(af, bcur[0], acc[0], 0, 0, 0);
            acc[1] = __builtin_amdgcn_mfma_f32_16x16x32_bf16(af, bcur[1], acc[1], 0, 0, 0);
            bcur[0] = bnxt[0]; bcur[1] = bnxt[1];

            // -- substage C: mean_r (plane 4+g); prefetch plane 1 when g==0 --
            if (g == 0) {
                bnxt[0] = wsWf[(1 * 4 + half * 2 + 0) * 64 + lane];
                bnxt[1] = wsWf[(1 * 4 + half * 2 + 1) * 64 + lane];
            }
            #pragma unroll
            for (int j = 0; j < 8; ++j)
                av[j] = ((float)rrw[j] - cnt[j] * PBIASF) * rcp[j];
            #pragma unroll
            for (int j = 0; j < 8; ++j) af[j] = f2bf(av[j]);
            acc[0] = __builtin_amdgcn_mfma_f32_16x16x32_bf16(af, bcur[0], acc[0], 0, 0, 0);
            acc[1] = __builtin_amdgcn_mfma_f32_16x16x32_bf16(af, bcur[1], acc[1], 0, 0, 0);
            bcur[0] = bnxt[0]; bcur[1] = bnxt[1];
        }

        // ---- epilogue: +bias, store x, BN partials. C/D: col=lane&15, row=quad*4+i ----
        #pragma unroll
        for (int tt = 0; tt < 2; ++tt) {
            const int t = half * 2 + tt;
            const float bias = bvec[t * 16 + col];
            #pragma unroll
            for (int i = 0; i < 4; ++i) {
                const int row = gbase + quad * 4 + i;
                if (row < M) {
                    const float xv = acc[tt][i] + bias;
                    xout[(size_t)row * 64 + t * 16 + col] = xv;
                    psum[tt] += xv;
                    psq[tt]  += xv * xv;
                }
            }
        }
    }

    // ---- BN partials: quad-reduce; lanes 0..31 carry this wave's 32 channels ----
    #pragma unroll
    for (int tt = 0; tt < 2; ++tt) {
        psum[tt] += __shfl_xor(psum[tt], 16);
        psum[tt] += __shfl_xor(psum[tt], 32);
        psq[tt]  += __shfl_xor(psq[tt], 16);
        psq[tt]  += __shfl_xor(psq[tt], 32);
    }
    // lane<32: quad in {0,1} selects tt; ch = half*32 + quad*16 + col = (2*half+tt)*16 + col
    const float myS = (quad & 1) ? psum[1] : psum[0];
    const float myQ = (quad & 1) ? psq[1]  : psq[0];
    const int gw = blockIdx.x * 2 + wave;
    if (lane < 32) {
        unsigned long long* dst = totals + (gw & (REPS - 1)) * 128 + half * 32 + lane;
        atomicAdd(dst,      (unsigned long long)(long long)(myS * TSC));
        atomicAdd(dst + 64, (unsigned long long)(long long)(myQ * TSC));
    }
}

__global__ __launch_bounds__(256)
void k3_bn_apply(float4* __restrict__ x,
                 const unsigned long long* __restrict__ totals,
                 const float* __restrict__ gamma,
                 const float* __restrict__ beta,
                 float invM, int n4)
{
    __shared__ float sT[128];
    __shared__ float sa[64];
    __shared__ float sc[64];
    const int t = threadIdx.x;
    if (t < 128) {   // sum replicas: deterministic across blocks
        long long s = 0;
        #pragma unroll
        for (int rep = 0; rep < REPS; ++rep) s += (long long)totals[rep * 128 + t];
        sT[t] = (float)s * (invM * INV_TSC);
    }
    __syncthreads();
    if (t < 64) {
        const float mu   = sT[t];
        const float q    = sT[64 + t];
        const float var  = q - mu * mu;
        const float rstd = 1.0f / sqrtf(var + 1e-5f);
        const float a    = gamma[t] * rstd;
        sa[t] = a;
        sc[t] = beta[t] - mu * a;
    }
    __syncthreads();
    const int stride = gridDim.x * 256;
    for (int i = blockIdx.x * 256 + t; i < n4; i += stride) {
        const float4 a = ((const float4*)sa)[i & 15];   // 64 ch = 16 float4
        const float4 c = ((const float4*)sc)[i & 15];
        float4 v = x[i];
        v.x = fmaxf(fmaf(v.x, a.x, c.x), 0.f);
        v.y = fmaxf(fmaf(v.y, a.y, c.y), 0.f);
        v.z = fmaxf(fmaf(v.z, a.z, c.z), 0.f);
        v.w = fmaxf(fmaf(v.w, a.w, c.w), 0.f);
        x[i] = v;
    }
}

extern "C" void kernel_launch(void* const* d_in, const int* in_sizes, int n_in,
                              void* d_out, int out_size, void* d_ws, size_t ws_size,
                              hipStream_t stream) {
    const uint2*  feat2 = (const uint2*)d_in[0];   // [M,64,4] fp32 viewed as uint2 pairs
    const int*    nump  = (const int*)d_in[1];     // [M]
    // d_in[2] = coors (unused)
    const float*  W     = (const float*)d_in[3];   // [64,192]
    const float*  bvec  = (const float*)d_in[4];   // [64]
    const float*  gamma = (const float*)d_in[5];   // [64]
    const float*  beta  = (const float*)d_in[6];   // [64]

    const int M = in_sizes[1];
    float* xout = (float*)d_out;
    short* wsW  = (short*)d_ws;                                   // [24*64*8] bf16 B-fragments
    unsigned long long* totals =
        (unsigned long long*)((char*)d_ws + 24 * 64 * 8 * sizeof(short));  // [REPS*128] u64

    k0_prep<<<16, 256, 0, stream>>>(W, wsW, totals);

    const int nblk = (M + 15) / 16;   // 16 rows/block (one wave pair)
    k1_hist_mfma<<<nblk, 128, 0, stream>>>(feat2, nump, (const bf16x8*)wsW, bvec, xout, totals, M);

    // k3 grid: memory-bound pass (51.2 MB r+w); 391 blocks (~6 waves/CU) was under-occupied.
    // Cap at 2048 grid-stride blocks per G11.
    const int n4 = out_size / 4;
    int nblk3 = (n4 + 255) / 256;
    if (nblk3 > 2048) nblk3 = 2048;
    k3_bn_apply<<<nblk3, 256, 0, stream>>>((float4*)d_out, totals, gamma, beta,
                                           1.0f / (float)M, n4);
}